// Round 21
// baseline (102.561 us; speedup 1.0000x reference)
//
#include <hip/hip_runtime.h>
#include <hip/hip_bf16.h>
#include <math.h>

#define T_DIM 1024
#define B_DIM 32
#define DIMF 512
#define DIMH 512
#define DIMS 1024
#define DIMW 512

typedef __attribute__((ext_vector_type(8))) short short8;
typedef __attribute__((ext_vector_type(4))) float f32x4;

__device__ __forceinline__ unsigned f2bf1(float x) {
    unsigned a = __float_as_uint(x);
    return (a + 0x7FFFu + ((a >> 16) & 1u)) >> 16;
}
__device__ __forceinline__ unsigned f2bf2(float lo, float hi) {
    return f2bf1(lo) | (f2bf1(hi) << 16);
}
__device__ __forceinline__ float fast_tanh(float x) {
    return 1.f - __fdividef(2.f, 1.f + __expf(x + x));
}
__device__ __forceinline__ unsigned short bf1(float x) {
    __hip_bfloat16 b = __float2bfloat16(x);
    return *reinterpret_cast<unsigned short*>(&b);
}
__device__ __forceinline__ short8 pack8(float4 a, float4 c) {
    union { unsigned short us[8]; short8 s; } u;
    u.us[0] = bf1(a.x); u.us[1] = bf1(a.y); u.us[2] = bf1(a.z); u.us[3] = bf1(a.w);
    u.us[4] = bf1(c.x); u.us[5] = bf1(c.y); u.us[6] = bf1(c.z); u.us[7] = bf1(c.w);
    return u.s;
}

// async global->LDS, 16B/lane; LDS dest wave-uniform, global src per-lane
__device__ __forceinline__ void gl16(const unsigned short* g, unsigned short* l) {
    __builtin_amdgcn_global_load_lds(
        (const __attribute__((address_space(1))) unsigned int*)g,
        (__attribute__((address_space(3))) unsigned int*)l, 16, 0, 0);
}
__device__ __forceinline__ void gl16f(const float* g, float* l) {
    __builtin_amdgcn_global_load_lds(
        (const __attribute__((address_space(1))) unsigned int*)g,
        (__attribute__((address_space(3))) unsigned int*)l, 16, 0, 0);
}

// ================= merged prep kernel (r17/r19-verified branches) =================
// [0,nPack): hB pack; [+512): G=F@Uw; [+512): VwT/P; [+64): SW partials.
__global__ void __launch_bounds__(256) k_prep_all(
    const float* __restrict__ F, const float* __restrict__ Uw,
    const float* __restrict__ Vw, const float* __restrict__ a_prev,
    const float* __restrict__ s_prev, const float* __restrict__ Ww,
    const float* __restrict__ Vb, const float* __restrict__ h,
    unsigned short* __restrict__ GT, unsigned short* __restrict__ VwT,
    unsigned short* __restrict__ P, float* __restrict__ SWp,
    unsigned short* __restrict__ hB, int nPack) {
    __shared__ float sh[8192];
    const int bz = blockIdx.x;
    const int tid = threadIdx.x;

    if (bz < nPack) {
        for (unsigned i = bz * 256 + tid; i < 32768u * 64; i += (unsigned)nPack * 256) {
            const int r = i >> 6, c8 = (i & 63) * 8;
            const int bb = r >> 10, t = r & 1023;
            const float* src = h + ((size_t)(t * 32 + bb)) * 512 + c8;
            const float4 v0 = *(const float4*)(src);
            const float4 v1 = *(const float4*)(src + 4);
            union { unsigned short us[8]; uint4 u4; } o;
            o.us[0] = bf1(v0.x); o.us[1] = bf1(v0.y);
            o.us[2] = bf1(v0.z); o.us[3] = bf1(v0.w);
            o.us[4] = bf1(v1.x); o.us[5] = bf1(v1.y);
            o.us[6] = bf1(v1.z); o.us[7] = bf1(v1.w);
            *(uint4*)(hB + (size_t)r * 512 + c8) = o.u4;
        }
        return;
    }
    const int bz2 = bz - nPack;
    if (bz2 < 512) {
        const int rt = bz2 & 63, ct = bz2 >> 6;
        const int r0g = rt * 16;
        const float4* Fv = (const float4*)(F + (size_t)r0g * DIMF);
        float4* shv = (float4*)sh;
        for (int i = tid; i < 16 * DIMF / 4; i += 256) shv[i] = Fv[i];
        __syncthreads();
        const int c = ct * 64 + (tid & 63);
        const int r0 = (tid >> 6) * 4;
        float acc[4] = {0.f, 0.f, 0.f, 0.f};
        for (int k = 0; k < DIMF; ++k) {
            const float bv = Uw[(size_t)k * DIMW + c];
#pragma unroll
            for (int j = 0; j < 4; ++j)
                acc[j] = fmaf(sh[(r0 + j) * DIMF + k], bv, acc[j]);
        }
        uint2 o;
        o.x = f2bf2(acc[0], acc[1]);
        o.y = f2bf2(acc[2], acc[3]);
        *(uint2*)(GT + (size_t)c * T_DIM + r0g + r0) = o;
        return;
    }
    const int bz3 = bz2 - 512;
    if (bz3 < 512) {
        if (bz3 < 256) {
            const int k0 = (bz3 >> 4) * 32, n0 = (bz3 & 15) * 32;
            const int x = tid & 31, y = tid >> 5;
#pragma unroll
            for (int i = 0; i < 4; ++i)
                sh[(y + 8 * i) * 33 + x] = Vw[(size_t)(k0 + y + 8 * i) * DIMW + n0 + x];
            __syncthreads();
#pragma unroll
            for (int i = 0; i < 4; ++i) {
                const int n = n0 + y + 8 * i;
                VwT[(size_t)n * DIMH + k0 + x] = (unsigned short)f2bf1(sh[x * 33 + y + 8 * i]);
            }
        } else {
            const int bs = bz3 - 256;
            const int b = bs >> 3, s = bs & 7;
            for (int i = tid; i < 2048; i += 256) {
                const int j = i + s;
                float v = 0.f;
                if (j >= 512 && j < 1536) v = a_prev[(size_t)b * T_DIM + j - 512];
                P[(size_t)bs * 2048 + i] = (unsigned short)f2bf1(v);
            }
        }
        return;
    }
    {
        const int bz4 = bz3 - 512;
        const int c0 = (bz4 & 15) * 32, q = bz4 >> 4;
        float (*shb)[256] = (float(*)[256])sh;
        for (int i = tid; i < 32 * 64; i += 256) {
            const int r = i >> 6, c4 = (i & 63) * 4;
            *(float4*)&shb[r][c4] = *(const float4*)(s_prev + (size_t)r * DIMS + q * 256 + c4);
        }
        __syncthreads();
        const int c  = c0 + (tid & 31);
        const int bg = tid >> 5;
        float acc[4];
#pragma unroll
        for (int j = 0; j < 4; ++j) acc[j] = (q == 0) ? Vb[c] : 0.f;
        const float* W = Ww + (size_t)q * 256 * DIMW;
        for (int k = 0; k < 256; ++k) {
            const float w = W[(size_t)k * DIMW + c];
#pragma unroll
            for (int j = 0; j < 4; ++j)
                acc[j] = fmaf(shb[bg + 8 * j][k], w, acc[j]);
        }
#pragma unroll
        for (int j = 0; j < 4; ++j)
            SWp[((size_t)q * B_DIM + bg + 8 * j) * DIMW + c] = acc[j];
    }
}

// ======== k_main tall-tile: 256(M)x128(N), 8 waves (4wm x 2wn), wave 64x64, all-gl16 ========
// grid 512 (XCD-swizzled), 512 threads, BK=64, single-buffered 48 KB (3 blocks/CU)
__global__ void __launch_bounds__(512, 4) k_main_t(
    const unsigned short* __restrict__ hB, const unsigned short* __restrict__ VwT,
    const unsigned short* __restrict__ GT, const unsigned short* __restrict__ P,
    const float* __restrict__ SWp, const float* __restrict__ ww,
    float* __restrict__ ep) {
    __shared__ unsigned short As2[256 * 64];   // 32 KB
    __shared__ unsigned short Bs[128 * 64];    // 16 KB

    const int bid = blockIdx.x;
    const int wg  = (bid & 7) * 64 + (bid >> 3);    // bijective: 512 % 8 == 0
    const int x = wg & 3, yy = wg >> 2;             // x: w-tile, yy: 0..127
    const int w0 = x * 128;
    const int b  = yy >> 2;
    const int t0 = (yy & 3) * 256;

    const int tid  = threadIdx.x;
    const int lane = tid & 63;
    const int wv   = tid >> 6;                      // 0..7
    const int wm = wv >> 1, wn = wv & 1;            // 4 x 2
    const int g = lane >> 4, r16 = lane & 15;
    const int s7 = r16 & 7;

    f32x4 acc[4][4];
#pragma unroll
    for (int m = 0; m < 4; ++m)
#pragma unroll
        for (int n = 0; n < 4; ++n) acc[m][n] = (f32x4)0.f;

    const int kstart = max(0, t0 - 512);
    const int kend   = min(T_DIM - 1, t0 + 766);
    const int NS2    = (kend - kstart + 64) >> 6;   // ceil; kstart+NS2*64 <= 1024
    const int NT     = 8 + NS2;

    // ---- staging sources (pre-swizzle both sides, r17-verified pattern) ----
    const int rB = lane >> 3;                       // row-in-8 (= row&7)
    const int cB = ((lane & 7) ^ rB) * 8;
    // A (hB bf16, 256 rows): 4 gl16/wave, rows wv*32 + q*8 + rB
    const unsigned short* hSb[4];
#pragma unroll
    for (int q = 0; q < 4; ++q)
        hSb[q] = hB + ((size_t)(b * 1024 + t0 + wv * 32 + q * 8 + rB)) * 512 + cB;
    // B (128 rows): 2 gl16/wave, rows wv*16 + q*8 + rB
    const unsigned short* vS[2];
    const unsigned short* gS[2];
#pragma unroll
    for (int q = 0; q < 2; ++q) {
        vS[q] = VwT + (size_t)(w0 + wv * 16 + q * 8 + rB) * DIMH + cB;
        gS[q] = GT  + (size_t)(w0 + wv * 16 + q * 8 + rB) * T_DIM + kstart + cB;
    }
    // part2 A from staggered P: 4 gl16/wave (zero-padded -> over-read K-steps are harmless)
    const unsigned short* Pb = P + (size_t)b * 8 * 2048;
    const unsigned short* pS[4];
#pragma unroll
    for (int q = 0; q < 4; ++q) {
        const int row = wv * 32 + q * 8 + rB;
        const int jb = kstart + ((lane & 7) ^ rB) * 8 + 1024 - (t0 + row);  // in [1,2040]
        const int sj = jb & 7;
        pS[q] = Pb + sj * 2048 + (jb - sj);
    }
    const bool zrow = (t0 + wm * 64 + r16 == 0);    // only wm=0,r16=0,t0=0

    // ================= part 1: h^T @ Vw, 8 steps of K=64 =================
    for (int k0 = 0; k0 < DIMH; k0 += 64) {
        __syncthreads();   // previous step's LDS reads done
#pragma unroll
        for (int q = 0; q < 4; ++q) gl16(hSb[q] + k0, As2 + (wv * 32 + q * 8) * 64);
#pragma unroll
        for (int q = 0; q < 2; ++q) gl16(vS[q] + k0, Bs + (wv * 16 + q * 8) * 64);
        __syncthreads();   // staging visible

#pragma unroll
        for (int ks = 0; ks < 2; ++ks) {
            short8 af[4], bf[4];
#pragma unroll
            for (int m = 0; m < 4; ++m)
                af[m] = *(const short8*)&As2[(wm * 64 + m * 16 + r16) * 64 +
                                             ((ks * 4 + g) ^ s7) * 8];
#pragma unroll
            for (int n = 0; n < 4; ++n)
                bf[n] = *(const short8*)&Bs[(wn * 64 + n * 16 + r16) * 64 +
                                            ((ks * 4 + g) ^ s7) * 8];
#pragma unroll
            for (int m = 0; m < 4; ++m)
#pragma unroll
                for (int n = 0; n < 4; ++n)
                    acc[m][n] = __builtin_amdgcn_mfma_f32_16x16x32_bf16(
                        af[m], bf[n], acc[m][n], 0, 0, 0);
        }
    }

    // ================= part 2: Toeplitz(a) @ G, NS2 steps of K=64 =================
    for (int s2 = 0; s2 < NS2; ++s2) {
        const int o = s2 * 64;
        __syncthreads();
#pragma unroll
        for (int q = 0; q < 4; ++q) gl16(pS[q] + o, As2 + (wv * 32 + q * 8) * 64);
#pragma unroll
        for (int q = 0; q < 2; ++q) gl16(gS[q] + o, Bs + (wv * 16 + q * 8) * 64);
        __syncthreads();

#pragma unroll
        for (int ks = 0; ks < 2; ++ks) {
            short8 af[4], bf[4];
#pragma unroll
            for (int m = 0; m < 4; ++m)
                af[m] = *(const short8*)&As2[(wm * 64 + m * 16 + r16) * 64 +
                                             ((ks * 4 + g) ^ s7) * 8];
            if (zrow) af[0] = (short8)(short)0;   // f row t=0 is zero
#pragma unroll
            for (int n = 0; n < 4; ++n)
                bf[n] = *(const short8*)&Bs[(wn * 64 + n * 16 + r16) * 64 +
                                            ((ks * 4 + g) ^ s7) * 8];
#pragma unroll
            for (int m = 0; m < 4; ++m)
#pragma unroll
                for (int n = 0; n < 4; ++n)
                    acc[m][n] = __builtin_amdgcn_mfma_f32_16x16x32_bf16(
                        af[m], bf[n], acc[m][n], 0, 0, 0);
        }
    }

    // ---- epilogue: tanh, dot ww, 16-lane reduce, LDS gather -> 8 partials ----
    float swv[4], wwv[4];
#pragma unroll
    for (int n = 0; n < 4; ++n) {
        const int w = w0 + wn * 64 + n * 16 + r16;
        float sv = 0.f;
#pragma unroll
        for (int q = 0; q < 4; ++q)
            sv += SWp[((size_t)q * B_DIM + b) * DIMW + w];
        swv[n] = sv;
        wwv[n] = ww[w];
    }
    __syncthreads();   // main-loop LDS reads done before reuse
    float* Ered = (float*)&As2[0];   // [2 wn][256 rows] floats = 2 KB
#pragma unroll
    for (int m = 0; m < 4; ++m) {
#pragma unroll
        for (int reg = 0; reg < 4; ++reg) {
            float s = 0.f;
#pragma unroll
            for (int n = 0; n < 4; ++n)
                s = fmaf(fast_tanh(acc[m][n][reg] + swv[n]), wwv[n], s);
            s += __shfl_xor(s, 1, 64);
            s += __shfl_xor(s, 2, 64);
            s += __shfl_xor(s, 4, 64);
            s += __shfl_xor(s, 8, 64);
            if (r16 == 0)
                Ered[wn * 256 + wm * 64 + m * 16 + g * 4 + reg] = s;
        }
    }
    __syncthreads();
    {
        const int p = tid >> 8, row = tid & 255;     // p: wn
        ep[((size_t)(x * 2 + p) * B_DIM + b) * T_DIM + t0 + row] = Ered[p * 256 + row];
    }
}

// ---------------- fallback: r20-verified f32-path kernel (no hB needed) ----------------
__global__ void __launch_bounds__(512, 4) k_main_s(
    const float* __restrict__ hF, const unsigned short* __restrict__ VwT,
    const unsigned short* __restrict__ GT, const unsigned short* __restrict__ P,
    const float* __restrict__ SWp, const float* __restrict__ ww,
    float* __restrict__ ep) {
    __shared__ __align__(16) float AsF[8192];
    __shared__ unsigned short Bs[8192];
    unsigned short* As2 = (unsigned short*)AsF;

    const int bid = blockIdx.x;
    const int wg  = (bid & 7) * 128 + (bid >> 3);
    const int x = wg & 3, yy = wg >> 2;
    const int w0 = x * 128;
    const int b  = yy >> 3;
    const int t0 = (yy & 7) * 128;

    const int tid  = threadIdx.x;
    const int lane = tid & 63;
    const int wv   = tid >> 6;
    const int wm = wv >> 2, wn = wv & 3;
    const int g = lane >> 4, r16 = lane & 15;
    const int s7 = r16 & 7;

    f32x4 acc[4][2];
#pragma unroll
    for (int m = 0; m < 4; ++m)
#pragma unroll
        for (int n = 0; n < 2; ++n) acc[m][n] = (f32x4)0.f;

    const int kstart = max(0, t0 - 512);
    const int kend   = min(T_DIM - 1, t0 + 639);
    const int NS2    = (kend - kstart + 1) >> 6;

    const int rl = lane >> 4, cl = lane & 15;
    const float* hS[4];
#pragma unroll
    for (int q = 0; q < 4; ++q) {
        const int row = wv * 16 + q * 4 + rl;
        hS[q] = hF + ((size_t)(t0 + row) * B_DIM + b) * DIMH + ((cl ^ (row & 7)) << 2);
    }
    const int rB = lane >> 3;
    const int cB = ((lane & 7) ^ rB) * 8;
    const unsigned short* vS[2];
    const unsigned short* gS[2];
#pragma unroll
    for (int q = 0; q < 2; ++q) {
        vS[q] = VwT + (size_t)(w0 + wv * 16 + q * 8 + rB) * DIMH + cB;
        gS[q] = GT  + (size_t)(w0 + wv * 16 + q * 8 + rB) * T_DIM + kstart + cB;
    }
    const unsigned short* Pb = P + (size_t)b * 8 * 2048;
    const unsigned short* pS[2];
#pragma unroll
    for (int q = 0; q < 2; ++q) {
        const int row = wv * 16 + q * 8 + rB;
        const int jb = kstart + ((lane & 7) ^ rB) * 8 + 1024 - (t0 + row);
        const int sj = jb & 7;
        pS[q] = Pb + sj * 2048 + (jb - sj);
    }
    const bool zrow = (t0 + wm * 64 + r16 == 0);

    for (int k0 = 0; k0 < DIMH; k0 += 64) {
        __syncthreads();
#pragma unroll
        for (int q = 0; q < 4; ++q) gl16f(hS[q] + k0, AsF + (wv * 16 + q * 4) * 64);
#pragma unroll
        for (int q = 0; q < 2; ++q) gl16(vS[q] + k0, Bs + (wv * 16 + q * 8) * 64);
        __syncthreads();
#pragma unroll
        for (int ks = 0; ks < 2; ++ks) {
            short8 af[4], bf[2];
#pragma unroll
            for (int m = 0; m < 4; ++m) {
                const int base = (wm * 64 + m * 16 + r16) * 64;
                const int clo = ((ks * 8 + 2 * g) ^ s7) * 4;
                const int chi = ((ks * 8 + 2 * g + 1) ^ s7) * 4;
                af[m] = pack8(*(const float4*)&AsF[base + clo],
                              *(const float4*)&AsF[base + chi]);
            }
#pragma unroll
            for (int n = 0; n < 2; ++n)
                bf[n] = *(const short8*)&Bs[(wn * 32 + n * 16 + r16) * 64 +
                                            ((ks * 4 + g) ^ s7) * 8];
#pragma unroll
            for (int m = 0; m < 4; ++m)
#pragma unroll
                for (int n = 0; n < 2; ++n)
                    acc[m][n] = __builtin_amdgcn_mfma_f32_16x16x32_bf16(
                        af[m], bf[n], acc[m][n], 0, 0, 0);
        }
    }
    for (int s2 = 0; s2 < NS2; ++s2) {
        const int o = s2 * 64;
        __syncthreads();
#pragma unroll
        for (int q = 0; q < 2; ++q) gl16(pS[q] + o, As2 + (wv * 16 + q * 8) * 64);
#pragma unroll
        for (int q = 0; q < 2; ++q) gl16(gS[q] + o, Bs + (wv * 16 + q * 8) * 64);
        __syncthreads();
#pragma unroll
        for (int ks = 0; ks < 2; ++ks) {
            short8 af[4], bf[2];
#pragma unroll
            for (int m = 0; m < 4; ++m)
                af[m] = *(const short8*)&As2[(wm * 64 + m * 16 + r16) * 64 +
                                             ((ks * 4 + g) ^ s7) * 8];
            if (zrow) af[0] = (short8)(short)0;
#pragma unroll
            for (int n = 0; n < 2; ++n)
                bf[n] = *(const short8*)&Bs[(wn * 32 + n * 16 + r16) * 64 +
                                            ((ks * 4 + g) ^ s7) * 8];
#pragma unroll
            for (int m = 0; m < 4; ++m)
#pragma unroll
                for (int n = 0; n < 2; ++n)
                    acc[m][n] = __builtin_amdgcn_mfma_f32_16x16x32_bf16(
                        af[m], bf[n], acc[m][n], 0, 0, 0);
        }
    }
    float swv[2], wwv[2];
#pragma unroll
    for (int n = 0; n < 2; ++n) {
        const int w = w0 + wn * 32 + n * 16 + r16;
        float sv = 0.f;
#pragma unroll
        for (int q = 0; q < 4; ++q)
            sv += SWp[((size_t)q * B_DIM + b) * DIMW + w];
        swv[n] = sv;
        wwv[n] = ww[w];
    }
    __syncthreads();
    float* Ered = (float*)&AsF[0];
#pragma unroll
    for (int m = 0; m < 4; ++m) {
#pragma unroll
        for (int reg = 0; reg < 4; ++reg) {
            float s = 0.f;
#pragma unroll
            for (int n = 0; n < 2; ++n)
                s = fmaf(fast_tanh(acc[m][n][reg] + swv[n]), wwv[n], s);
            s += __shfl_xor(s, 1, 64);
            s += __shfl_xor(s, 2, 64);
            s += __shfl_xor(s, 4, 64);
            s += __shfl_xor(s, 8, 64);
            if (r16 == 0)
                Ered[wn * 128 + wm * 64 + m * 16 + g * 4 + reg] = s;
        }
    }
    __syncthreads();
    if (tid < 256) {
        const int p = tid >> 7, row = tid & 127;
        const float v = Ered[p * 128 + row] + Ered[(p + 2) * 128 + row];
        ep[((size_t)(x * 2 + p) * B_DIM + b) * T_DIM + t0 + row] = v;
    }
}

// ---------------- softmax over t per batch (sums 8 e-partials, r20-verified) ----------------
__device__ __forceinline__ float decode_beta(const void* p) {
    const int iv = *(const int*)p;
    const float fv = __int_as_float(iv);
    const float afv = fabsf(fv);
    if (afv >= 1e-6f && afv <= 1e6f) return fv;
    return (float)iv;
}

__global__ void k_softmax(const float* __restrict__ ep, const void* __restrict__ beta_p,
                          float* __restrict__ out) {
    const int b = blockIdx.x;
    const float beta = decode_beta(beta_p);
    __shared__ float redm[4];
    __shared__ float reds[4];
    float v[4];
    float m = -INFINITY;
#pragma unroll
    for (int i = 0; i < 4; ++i) {
        const int t = threadIdx.x * 4 + i;
        float ev = 0.f;
#pragma unroll
        for (int xq = 0; xq < 8; ++xq)
            ev += ep[((size_t)xq * B_DIM + b) * T_DIM + t];
        v[i] = beta * ev;
        m = fmaxf(m, v[i]);
    }
    for (int off = 1; off < 64; off <<= 1) m = fmaxf(m, __shfl_xor(m, off, 64));
    const int wid = threadIdx.x >> 6, lane = threadIdx.x & 63;
    if (lane == 0) redm[wid] = m;
    __syncthreads();
    m = fmaxf(fmaxf(redm[0], redm[1]), fmaxf(redm[2], redm[3]));
    float s = 0.f;
    float ex[4];
#pragma unroll
    for (int i = 0; i < 4; ++i) { ex[i] = expf(v[i] - m); s += ex[i]; }
    for (int off = 1; off < 64; off <<= 1) s += __shfl_xor(s, off, 64);
    if (lane == 0) reds[wid] = s;
    __syncthreads();
    s = reds[0] + reds[1] + reds[2] + reds[3];
    const float inv = 1.f / s;
#pragma unroll
    for (int i = 0; i < 4; ++i)
        out[(size_t)b * T_DIM + threadIdx.x * 4 + i] = ex[i] * inv;
}

extern "C" void kernel_launch(void* const* d_in, const int* in_sizes, int n_in,
                              void* d_out, int out_size, void* d_ws, size_t ws_size,
                              hipStream_t stream) {
    const float* F      = (const float*)d_in[0];
    const float* a_prev = (const float*)d_in[1];
    const float* s_prev = (const float*)d_in[2];
    const float* h      = (const float*)d_in[3];
    const float* Ww     = (const float*)d_in[4];
    const float* Vw     = (const float*)d_in[5];
    const float* Vb     = (const float*)d_in[6];
    const float* Uw     = (const float*)d_in[7];
    const float* ww     = (const float*)d_in[8];
    const void*  beta_p = d_in[9];
    float* out = (float*)d_out;

    char* ws = (char*)d_ws;
    unsigned short* GT  = (unsigned short*)(ws);                              // 1 MB
    unsigned short* VwT = (unsigned short*)(ws + (1u << 20));                 // 512 KB
    unsigned short* P   = (unsigned short*)(ws + (1u << 20) + (512u << 10));  // 1 MB
    float* SWp = (float*)(ws + (2u << 20) + (512u << 10));                    // 256 KB
    float* ep  = (float*)(ws + (2u << 20) + (768u << 10));                    // 1 MB (8 partials)
    unsigned short* hB = (unsigned short*)(ws + (4u << 20));                  // 32 MB if available

    const bool big = ws_size >= (36ull << 20);
    const int nPack = big ? 1024 : 0;

    k_prep_all<<<dim3(nPack + 1088), 256, 0, stream>>>(
        F, Uw, Vw, a_prev, s_prev, Ww, Vb, h, GT, VwT, P, SWp, hB, nPack);
    if (big) {
        k_main_t<<<dim3(512), 512, 0, stream>>>(hB, VwT, GT, P, SWp, ww, ep);
    } else {
        k_main_s<<<dim3(1024), 512, 0, stream>>>(h, VwT, GT, P, SWp, ww, ep);
    }
    k_softmax<<<dim3(32), 256, 0, stream>>>(ep, beta_p, out);
}

// Round 22
// 92.104 us; speedup vs baseline: 1.1135x; 1.1135x over previous
//
#include <hip/hip_runtime.h>
#include <hip/hip_bf16.h>
#include <math.h>

#define T_DIM 1024
#define B_DIM 32
#define DIMF 512
#define DIMH 512
#define DIMS 1024
#define DIMW 512

typedef __attribute__((ext_vector_type(8))) short short8;
typedef __attribute__((ext_vector_type(4))) float f32x4;

__device__ __forceinline__ unsigned f2bf1(float x) {
    unsigned a = __float_as_uint(x);
    return (a + 0x7FFFu + ((a >> 16) & 1u)) >> 16;
}
__device__ __forceinline__ unsigned f2bf2(float lo, float hi) {
    return f2bf1(lo) | (f2bf1(hi) << 16);
}
__device__ __forceinline__ float fast_tanh(float x) {
    return 1.f - __fdividef(2.f, 1.f + __expf(x + x));
}
__device__ __forceinline__ unsigned short bf1(float x) {
    __hip_bfloat16 b = __float2bfloat16(x);
    return *reinterpret_cast<unsigned short*>(&b);
}
// 8 f32 (two float4) -> short8 bf16 (compiler emits v_cvt_pk_bf16_f32)
__device__ __forceinline__ short8 pack8(float4 a, float4 c) {
    union { unsigned short us[8]; short8 s; } u;
    u.us[0] = bf1(a.x); u.us[1] = bf1(a.y); u.us[2] = bf1(a.z); u.us[3] = bf1(a.w);
    u.us[4] = bf1(c.x); u.us[5] = bf1(c.y); u.us[6] = bf1(c.z); u.us[7] = bf1(c.w);
    return u.s;
}

// async global->LDS, 16B/lane; LDS dest wave-uniform, global src per-lane
__device__ __forceinline__ void gl16(const unsigned short* g, unsigned short* l) {
    __builtin_amdgcn_global_load_lds(
        (const __attribute__((address_space(1))) unsigned int*)g,
        (__attribute__((address_space(3))) unsigned int*)l, 16, 0, 0);
}
__device__ __forceinline__ void gl16f(const float* g, float* l) {
    __builtin_amdgcn_global_load_lds(
        (const __attribute__((address_space(1))) unsigned int*)g,
        (__attribute__((address_space(3))) unsigned int*)l, 16, 0, 0);
}

// ================= merged prep kernel (r20-verified, pack-free) =================
// blocks [0,512): G=F@Uw -> GT; [512,1024): VwT/P pack; [1024,1088): SW partials.
__global__ void __launch_bounds__(256) k_prep_all(
    const float* __restrict__ F, const float* __restrict__ Uw,
    const float* __restrict__ Vw, const float* __restrict__ a_prev,
    const float* __restrict__ s_prev, const float* __restrict__ Ww,
    const float* __restrict__ Vb,
    unsigned short* __restrict__ GT, unsigned short* __restrict__ VwT,
    unsigned short* __restrict__ P, float* __restrict__ SWp) {
    __shared__ float sh[8192];
    const int bz = blockIdx.x;
    const int tid = threadIdx.x;

    if (bz < 512) {
        const int rt = bz & 63, ct = bz >> 6;
        const int r0g = rt * 16;
        const float4* Fv = (const float4*)(F + (size_t)r0g * DIMF);
        float4* shv = (float4*)sh;
        for (int i = tid; i < 16 * DIMF / 4; i += 256) shv[i] = Fv[i];
        __syncthreads();
        const int c = ct * 64 + (tid & 63);
        const int r0 = (tid >> 6) * 4;
        float acc[4] = {0.f, 0.f, 0.f, 0.f};
        for (int k = 0; k < DIMF; ++k) {
            const float bv = Uw[(size_t)k * DIMW + c];
#pragma unroll
            for (int j = 0; j < 4; ++j)
                acc[j] = fmaf(sh[(r0 + j) * DIMF + k], bv, acc[j]);
        }
        uint2 o;
        o.x = f2bf2(acc[0], acc[1]);
        o.y = f2bf2(acc[2], acc[3]);
        *(uint2*)(GT + (size_t)c * T_DIM + r0g + r0) = o;
        return;
    }
    const int bz3 = bz - 512;
    if (bz3 < 512) {
        if (bz3 < 256) {
            const int k0 = (bz3 >> 4) * 32, n0 = (bz3 & 15) * 32;
            const int x = tid & 31, y = tid >> 5;
#pragma unroll
            for (int i = 0; i < 4; ++i)
                sh[(y + 8 * i) * 33 + x] = Vw[(size_t)(k0 + y + 8 * i) * DIMW + n0 + x];
            __syncthreads();
#pragma unroll
            for (int i = 0; i < 4; ++i) {
                const int n = n0 + y + 8 * i;
                VwT[(size_t)n * DIMH + k0 + x] = (unsigned short)f2bf1(sh[x * 33 + y + 8 * i]);
            }
        } else {
            const int bs = bz3 - 256;
            const int b = bs >> 3, s = bs & 7;
            for (int i = tid; i < 2048; i += 256) {
                const int j = i + s;
                float v = 0.f;
                if (j >= 512 && j < 1536) v = a_prev[(size_t)b * T_DIM + j - 512];
                P[(size_t)bs * 2048 + i] = (unsigned short)f2bf1(v);
            }
        }
        return;
    }
    {
        const int bz4 = bz3 - 512;
        const int c0 = (bz4 & 15) * 32, q = bz4 >> 4;
        float (*shb)[256] = (float(*)[256])sh;
        for (int i = tid; i < 32 * 64; i += 256) {
            const int r = i >> 6, c4 = (i & 63) * 4;
            *(float4*)&shb[r][c4] = *(const float4*)(s_prev + (size_t)r * DIMS + q * 256 + c4);
        }
        __syncthreads();
        const int c  = c0 + (tid & 31);
        const int bg = tid >> 5;
        float acc[4];
#pragma unroll
        for (int j = 0; j < 4; ++j) acc[j] = (q == 0) ? Vb[c] : 0.f;
        const float* W = Ww + (size_t)q * 256 * DIMW;
        for (int k = 0; k < 256; ++k) {
            const float w = W[(size_t)k * DIMW + c];
#pragma unroll
            for (int j = 0; j < 4; ++j)
                acc[j] = fmaf(shb[bg + 8 * j][k], w, acc[j]);
        }
#pragma unroll
        for (int j = 0; j < 4; ++j)
            SWp[((size_t)q * B_DIM + bg + 8 * j) * DIMW + c] = acc[j];
    }
}

// ======== k_main tall-tile pack-free: 256(M)x128(N), 8 waves (4wm x 2wn), all-gl16 ========
// grid 512 (XCD-swizzled), 512 threads, BK=64; A staged as raw f32 (cvt at frag-read);
// LDS = 64 KB (A f32) + 16 KB (B) = 80 KB -> 2 blocks/CU. Part2 A bf16 aliases AsF.
__global__ void __launch_bounds__(512, 4) k_main_t2(
    const float* __restrict__ hF, const unsigned short* __restrict__ VwT,
    const unsigned short* __restrict__ GT, const unsigned short* __restrict__ P,
    const float* __restrict__ SWp, const float* __restrict__ ww,
    float* __restrict__ ep) {
    __shared__ __align__(16) float AsF[256 * 64];   // 64 KB (part1 f32 A)
    __shared__ unsigned short Bs[128 * 64];         // 16 KB
    unsigned short* As2 = (unsigned short*)AsF;     // part2 bf16 A view (32 KB used)

    const int bid = blockIdx.x;
    const int wg  = (bid & 7) * 64 + (bid >> 3);    // bijective: 512 % 8 == 0
    const int x = wg & 3, yy = wg >> 2;
    const int w0 = x * 128;
    const int b  = yy >> 2;
    const int t0 = (yy & 3) * 256;

    const int tid  = threadIdx.x;
    const int lane = tid & 63;
    const int wv   = tid >> 6;                      // 0..7
    const int wm = wv >> 1, wn = wv & 1;            // 4 x 2
    const int g = lane >> 4, r16 = lane & 15;
    const int s7 = r16 & 7;

    f32x4 acc[4][4];
#pragma unroll
    for (int m = 0; m < 4; ++m)
#pragma unroll
        for (int n = 0; n < 4; ++n) acc[m][n] = (f32x4)0.f;

    const int kstart = max(0, t0 - 512);
    const int kend   = min(T_DIM - 1, t0 + 766);
    const int NS2    = (kend - kstart + 64) >> 6;   // ceil; kstart+NS2*64 <= 1024

    // ---- part1 A f32 gl16 sources (r20-verified pattern, 256 rows): 8 gl16/wave ----
    const int rl = lane >> 4, cl = lane & 15;       // row-in-4, 16B f32 chunk
    const float* hS[8];
#pragma unroll
    for (int q = 0; q < 8; ++q) {
        const int row = wv * 32 + q * 4 + rl;
        hS[q] = hF + ((size_t)(t0 + row) * B_DIM + b) * DIMH + ((cl ^ (row & 7)) << 2);
    }
    // ---- B sources (r21-verified pre-swizzle): 2 gl16/wave ----
    const int rB = lane >> 3;                       // row-in-8 (= row&7)
    const int cB = ((lane & 7) ^ rB) * 8;
    const unsigned short* vS[2];
    const unsigned short* gS[2];
#pragma unroll
    for (int q = 0; q < 2; ++q) {
        vS[q] = VwT + (size_t)(w0 + wv * 16 + q * 8 + rB) * DIMH + cB;
        gS[q] = GT  + (size_t)(w0 + wv * 16 + q * 8 + rB) * T_DIM + kstart + cB;
    }
    // ---- part2 A from staggered P (r21-verified): 4 gl16/wave over 256 rows ----
    const unsigned short* Pb = P + (size_t)b * 8 * 2048;
    const unsigned short* pS[4];
#pragma unroll
    for (int q = 0; q < 4; ++q) {
        const int row = wv * 32 + q * 8 + rB;
        const int jb = kstart + ((lane & 7) ^ rB) * 8 + 1024 - (t0 + row);  // in [1,2040]
        const int sj = jb & 7;
        pS[q] = Pb + sj * 2048 + (jb - sj);
    }
    const bool zrow = (t0 + wm * 64 + r16 == 0);    // only wm=0,r16=0,t0=0

    // ================= part 1: h^T @ Vw, 8 steps of K=64 =================
    for (int k0 = 0; k0 < DIMH; k0 += 64) {
        __syncthreads();   // previous step's LDS reads done
#pragma unroll
        for (int q = 0; q < 8; ++q) gl16f(hS[q] + k0, AsF + (wv * 32 + q * 4) * 64);
#pragma unroll
        for (int q = 0; q < 2; ++q) gl16(vS[q] + k0, Bs + (wv * 16 + q * 8) * 64);
        __syncthreads();   // staging visible

#pragma unroll
        for (int ks = 0; ks < 2; ++ks) {
            short8 af[4], bf[4];
#pragma unroll
            for (int m = 0; m < 4; ++m) {
                const int base = (wm * 64 + m * 16 + r16) * 64;
                const int clo = ((ks * 8 + 2 * g) ^ s7) * 4;
                const int chi = ((ks * 8 + 2 * g + 1) ^ s7) * 4;
                af[m] = pack8(*(const float4*)&AsF[base + clo],
                              *(const float4*)&AsF[base + chi]);
            }
#pragma unroll
            for (int n = 0; n < 4; ++n)
                bf[n] = *(const short8*)&Bs[(wn * 64 + n * 16 + r16) * 64 +
                                            ((ks * 4 + g) ^ s7) * 8];
#pragma unroll
            for (int m = 0; m < 4; ++m)
#pragma unroll
                for (int n = 0; n < 4; ++n)
                    acc[m][n] = __builtin_amdgcn_mfma_f32_16x16x32_bf16(
                        af[m], bf[n], acc[m][n], 0, 0, 0);
        }
    }

    // ================= part 2: Toeplitz(a) @ G, NS2 steps of K=64 =================
    for (int s2 = 0; s2 < NS2; ++s2) {
        const int o = s2 * 64;
        __syncthreads();
#pragma unroll
        for (int q = 0; q < 4; ++q) gl16(pS[q] + o, As2 + (wv * 32 + q * 8) * 64);
#pragma unroll
        for (int q = 0; q < 2; ++q) gl16(gS[q] + o, Bs + (wv * 16 + q * 8) * 64);
        __syncthreads();

#pragma unroll
        for (int ks = 0; ks < 2; ++ks) {
            short8 af[4], bf[4];
#pragma unroll
            for (int m = 0; m < 4; ++m)
                af[m] = *(const short8*)&As2[(wm * 64 + m * 16 + r16) * 64 +
                                             ((ks * 4 + g) ^ s7) * 8];
            if (zrow) af[0] = (short8)(short)0;   // f row t=0 is zero
#pragma unroll
            for (int n = 0; n < 4; ++n)
                bf[n] = *(const short8*)&Bs[(wn * 64 + n * 16 + r16) * 64 +
                                            ((ks * 4 + g) ^ s7) * 8];
#pragma unroll
            for (int m = 0; m < 4; ++m)
#pragma unroll
                for (int n = 0; n < 4; ++n)
                    acc[m][n] = __builtin_amdgcn_mfma_f32_16x16x32_bf16(
                        af[m], bf[n], acc[m][n], 0, 0, 0);
        }
    }

    // ---- epilogue (r21-verified): tanh, dot ww, 16-lane reduce, LDS gather -> 8 partials ----
    float swv[4], wwv[4];
#pragma unroll
    for (int n = 0; n < 4; ++n) {
        const int w = w0 + wn * 64 + n * 16 + r16;
        float sv = 0.f;
#pragma unroll
        for (int q = 0; q < 4; ++q)
            sv += SWp[((size_t)q * B_DIM + b) * DIMW + w];
        swv[n] = sv;
        wwv[n] = ww[w];
    }
    __syncthreads();   // main-loop LDS reads done before reuse
    float* Ered = (float*)&AsF[0];   // [2 wn][256 rows] floats = 2 KB
#pragma unroll
    for (int m = 0; m < 4; ++m) {
#pragma unroll
        for (int reg = 0; reg < 4; ++reg) {
            float s = 0.f;
#pragma unroll
            for (int n = 0; n < 4; ++n)
                s = fmaf(fast_tanh(acc[m][n][reg] + swv[n]), wwv[n], s);
            s += __shfl_xor(s, 1, 64);
            s += __shfl_xor(s, 2, 64);
            s += __shfl_xor(s, 4, 64);
            s += __shfl_xor(s, 8, 64);
            if (r16 == 0)
                Ered[wn * 256 + wm * 64 + m * 16 + g * 4 + reg] = s;
        }
    }
    __syncthreads();
    {
        const int p = tid >> 8, row = tid & 255;     // p: wn
        ep[((size_t)(x * 2 + p) * B_DIM + b) * T_DIM + t0 + row] = Ered[p * 256 + row];
    }
}

// ---------------- softmax over t per batch (sums 8 e-partials, r21-verified) ----------------
__device__ __forceinline__ float decode_beta(const void* p) {
    const int iv = *(const int*)p;
    const float fv = __int_as_float(iv);
    const float afv = fabsf(fv);
    if (afv >= 1e-6f && afv <= 1e6f) return fv;
    return (float)iv;
}

__global__ void k_softmax(const float* __restrict__ ep, const void* __restrict__ beta_p,
                          float* __restrict__ out) {
    const int b = blockIdx.x;
    const float beta = decode_beta(beta_p);
    __shared__ float redm[4];
    __shared__ float reds[4];
    float v[4];
    float m = -INFINITY;
#pragma unroll
    for (int i = 0; i < 4; ++i) {
        const int t = threadIdx.x * 4 + i;
        float ev = 0.f;
#pragma unroll
        for (int xq = 0; xq < 8; ++xq)
            ev += ep[((size_t)xq * B_DIM + b) * T_DIM + t];
        v[i] = beta * ev;
        m = fmaxf(m, v[i]);
    }
    for (int off = 1; off < 64; off <<= 1) m = fmaxf(m, __shfl_xor(m, off, 64));
    const int wid = threadIdx.x >> 6, lane = threadIdx.x & 63;
    if (lane == 0) redm[wid] = m;
    __syncthreads();
    m = fmaxf(fmaxf(redm[0], redm[1]), fmaxf(redm[2], redm[3]));
    float s = 0.f;
    float ex[4];
#pragma unroll
    for (int i = 0; i < 4; ++i) { ex[i] = expf(v[i] - m); s += ex[i]; }
    for (int off = 1; off < 64; off <<= 1) s += __shfl_xor(s, off, 64);
    if (lane == 0) reds[wid] = s;
    __syncthreads();
    s = reds[0] + reds[1] + reds[2] + reds[3];
    const float inv = 1.f / s;
#pragma unroll
    for (int i = 0; i < 4; ++i)
        out[(size_t)b * T_DIM + threadIdx.x * 4 + i] = ex[i] * inv;
}

extern "C" void kernel_launch(void* const* d_in, const int* in_sizes, int n_in,
                              void* d_out, int out_size, void* d_ws, size_t ws_size,
                              hipStream_t stream) {
    const float* F      = (const float*)d_in[0];
    const float* a_prev = (const float*)d_in[1];
    const float* s_prev = (const float*)d_in[2];
    const float* h      = (const float*)d_in[3];
    const float* Ww     = (const float*)d_in[4];
    const float* Vw     = (const float*)d_in[5];
    const float* Vb     = (const float*)d_in[6];
    const float* Uw     = (const float*)d_in[7];
    const float* ww     = (const float*)d_in[8];
    const void*  beta_p = d_in[9];
    float* out = (float*)d_out;

    char* ws = (char*)d_ws;
    unsigned short* GT  = (unsigned short*)(ws);                              // 1 MB
    unsigned short* VwT = (unsigned short*)(ws + (1u << 20));                 // 512 KB
    unsigned short* P   = (unsigned short*)(ws + (1u << 20) + (512u << 10));  // 1 MB
    float* SWp = (float*)(ws + (2u << 20) + (512u << 10));                    // 256 KB
    float* ep  = (float*)(ws + (2u << 20) + (768u << 10));                    // 1 MB (8 partials)

    k_prep_all<<<dim3(1088), 256, 0, stream>>>(
        F, Uw, Vw, a_prev, s_prev, Ww, Vb, GT, VwT, P, SWp);
    k_main_t2 <<<dim3(512),  512, 0, stream>>>(h, VwT, GT, P, SWp, ww, ep);
    k_softmax <<<dim3(32),   256, 0, stream>>>(ep, beta_p, out);
}